// Round 1
// baseline (145.827 us; speedup 1.0000x reference)
//
#include <hip/hip_runtime.h>
#include <stdint.h>
#include <stddef.h>

// ClusterLayer: q = normalize_rows( 1 / (1 + ||z-c||^2) )
// N=200000 rows, D=256, KC=256 clusters. fp32 in/out; cross-term via bf16 MFMA.

#define NTHREADS 512
#define D 256
#define KC 256

typedef __attribute__((ext_vector_type(8))) short short8;  // 8 bf16 (4 VGPRs)
typedef __attribute__((ext_vector_type(4))) float f32x4;   // MFMA accumulator

// fp32 -> bf16, round-to-nearest-even (branch-free)
__device__ __forceinline__ short f2bf(float f) {
    uint32_t u = __builtin_bit_cast(uint32_t, f);
    u += 0x7FFFu + ((u >> 16) & 1u);
    return (short)(u >> 16);
}

// One wave per cluster row: convert C (f32) -> Cb (bf16), compute csq[k] = ||c_k||^2.
__global__ void prep_kernel(const float* __restrict__ C,
                            unsigned short* __restrict__ Cb,
                            float* __restrict__ csq) {
    const int k = blockIdx.x;
    const int l = threadIdx.x;  // 0..63
    float4 v = *(const float4*)(C + k * D + l * 4);
    float s = v.x * v.x + v.y * v.y + v.z * v.z + v.w * v.w;
    ushort4 p;
    p.x = (unsigned short)f2bf(v.x);
    p.y = (unsigned short)f2bf(v.y);
    p.z = (unsigned short)f2bf(v.z);
    p.w = (unsigned short)f2bf(v.w);
    *(ushort4*)(Cb + k * D + l * 4) = p;
#pragma unroll
    for (int off = 32; off > 0; off >>= 1) s += __shfl_down(s, off);
    if (l == 0) csq[k] = s;
}

// 8 waves/block; each wave computes 16 full rows (all 256 clusters) so row
// normalization needs no cross-wave communication. Cb staged to LDS in two
// 64KB halves (d=0..127, d=128..255), XOR-swizzled against bank conflicts.
__global__ void __launch_bounds__(NTHREADS)
main_kernel(const float* __restrict__ z,
            const unsigned short* __restrict__ Cb,
            const float* __restrict__ csq,
            float* __restrict__ out, int nrows) {
    __shared__ unsigned char lds[65536];  // 256 clusters x 128 d x bf16, swizzled

    const int tid  = threadIdx.x;
    const int lane = tid & 63;
    const int wave = tid >> 6;
    const int l15  = lane & 15;
    const int lg   = lane >> 4;          // 0..3
    const int sw   = (l15 & 7) << 4;     // lane-constant XOR swizzle term

    int row0 = blockIdx.x * 128 + wave * 16;
    if (row0 > nrows - 16) row0 = nrows - 16;  // tail clamp: duplicate identical writes, benign

    // c_sq for this lane's 16 columns (col = ct*16 + l15), kept in regs
    float csqr[16];
#pragma unroll
    for (int ct = 0; ct < 16; ++ct) csqr[ct] = csq[ct * 16 + l15];

    // A-fragment source: lane reads z[row0 + l15][k = kk*32 + lg*8 .. +8]
    const float* zrow = z + (size_t)(row0 + l15) * D + lg * 8;

    f32x4 acc[16];
    const f32x4 zero4 = {0.f, 0.f, 0.f, 0.f};
#pragma unroll
    for (int ct = 0; ct < 16; ++ct) acc[ct] = zero4;
    float zsq_part = 0.f;

#pragma unroll
    for (int h = 0; h < 2; ++h) {
        if (h) __syncthreads();  // all reads of previous half done before overwrite
        // stage 64KB half: 4096 x 16B chunks, row stride 256B, swizzled
        for (int i = tid; i < 4096; i += NTHREADS) {
            const int r = i >> 4;     // cluster row
            const int c16 = i & 15;   // 16B chunk within half-row
            uint4 v = *(const uint4*)(Cb + r * D + h * 128 + c16 * 8);
            *(uint4*)(lds + r * 256 + ((c16 * 16) ^ ((r & 7) << 4))) = v;
        }
        __syncthreads();

#pragma unroll
        for (int kk = 0; kk < 4; ++kk) {
            const float* ap = zrow + h * 128 + kk * 32;
            float4 a0 = *(const float4*)(ap);
            float4 a1 = *(const float4*)(ap + 4);
            zsq_part += a0.x * a0.x + a0.y * a0.y + a0.z * a0.z + a0.w * a0.w +
                        a1.x * a1.x + a1.y * a1.y + a1.z * a1.z + a1.w * a1.w;
            short8 af;
            af[0] = f2bf(a0.x); af[1] = f2bf(a0.y); af[2] = f2bf(a0.z); af[3] = f2bf(a0.w);
            af[4] = f2bf(a1.x); af[5] = f2bf(a1.y); af[6] = f2bf(a1.z); af[7] = f2bf(a1.w);
            const int db = ((kk << 6) + (lg << 4)) ^ sw;  // swizzled byte offset in half-row
#pragma unroll
            for (int ct = 0; ct < 16; ++ct) {
                short8 bf = *(const short8*)(lds + (ct * 16 + l15) * 256 + db);
                acc[ct] = __builtin_amdgcn_mfma_f32_16x16x32_bf16(af, bf, acc[ct], 0, 0, 0);
            }
        }
    }

    // ||z_row||^2: lane holds partial for row l15 over its k-chunks; sum lane groups
    float zsq = zsq_part;
    zsq += __shfl_xor(zsq, 16);
    zsq += __shfl_xor(zsq, 32);
    // redistribute to C/D layout rows: row = lg*4 + j
    float zsqj[4];
#pragma unroll
    for (int j = 0; j < 4; ++j) zsqj[j] = __shfl(zsq, lg * 4 + j);

    // q = 1/(1+dist); accumulate per-lane partial row sums
    float rs[4] = {0.f, 0.f, 0.f, 0.f};
#pragma unroll
    for (int ct = 0; ct < 16; ++ct) {
#pragma unroll
        for (int j = 0; j < 4; ++j) {
            float dist = zsqj[j] + csqr[ct] - 2.0f * acc[ct][j];
            dist = fmaxf(dist, 0.f);
            float qv = 1.0f / (1.0f + dist);
            acc[ct][j] = qv;
            rs[j] += qv;
        }
    }
    // reduce row sums across the 16-lane column group
#pragma unroll
    for (int j = 0; j < 4; ++j) {
        float s = rs[j];
        s += __shfl_xor(s, 1);
        s += __shfl_xor(s, 2);
        s += __shfl_xor(s, 4);
        s += __shfl_xor(s, 8);
        rs[j] = 1.0f / s;
    }
    // store: lane writes col ct*16+l15 of rows row0 + lg*4 + j
#pragma unroll
    for (int j = 0; j < 4; ++j) {
        float* orow = out + (size_t)(row0 + lg * 4 + j) * KC + l15;
#pragma unroll
        for (int ct = 0; ct < 16; ++ct) orow[ct * 16] = acc[ct][j] * rs[j];
    }
}

extern "C" void kernel_launch(void* const* d_in, const int* in_sizes, int n_in,
                              void* d_out, int out_size, void* d_ws, size_t ws_size,
                              hipStream_t stream) {
    const float* zp = (const float*)d_in[0];
    const float* Cp = (const float*)d_in[1];
    const int N = in_sizes[0] / D;  // 200000
    unsigned short* Cb = (unsigned short*)d_ws;                       // 128KB bf16 centers
    float* csq = (float*)((char*)d_ws + (size_t)KC * D * sizeof(unsigned short));  // 1KB

    prep_kernel<<<KC, 64, 0, stream>>>(Cp, Cb, csq);
    const int nblk = (N + 127) / 128;
    main_kernel<<<nblk, NTHREADS, 0, stream>>>(zp, Cb, csq, (float*)d_out, N);
}